// Round 12
// baseline (388.581 us; speedup 1.0000x reference)
//
#include <hip/hip_runtime.h>
#include <cfloat>

// ============ INSTRUMENTATION ROUND ============
// sims x10, agg x40 internal reps (idempotent) so their dispatches exceed the
// ~270us harness fill kernels and surface in rocprof top-5 with full counters.
#define REP_SIMS 10
#define REP_AGG  40

// Shapes (fixed by reference)
#define Bb 4
#define Tt 12
#define Nn 307
#define Cc 64
#define TH 6000
#define Wn 200        // windows: starts = 0,30,...,5970
#define ROW (Nn*Cc)   // 19648 floats per time-row
#define NT (Tt*Nn)    // 3684
#define KTOP 10
#define NUMEL 943104.0f  // B*64*N*T

// sims decomposition: window x sixth-of-window (a sixth = exactly 2 rows = 157KB)
#define NS 6
#define SIXTH (2*ROW)    // 39296 floats
#define SIXTH4 (SIXTH/4) // 9824 float4s

// workspace layout (float offsets)
#define WS_MT   0                      // 4096  : Mt[c'*64+c]
#define WS_BC   4096                   // 64    : Bc[c]
#define WS_WVT  4160                   // 4096  : WvT[cc*64+o]
#define WS_QWL  (WS_WVT + 4096)        // 235776: QWl[t][n][c]
#define WS_PART (WS_QWL + Tt*ROW)      // 1200  : part[s][w]
#define WS_CORR (WS_PART + NS*Wn)      // 10    : softmax weights
#define WS_IDX  (WS_CORR + KTOP)       // 10    : window indices (int)

// ---------- Kernel A: Mt = Wk^T Wq (transposed), Bc, WvT ----------
__global__ void prep_kernel(const float* __restrict__ Wq, const float* __restrict__ bq,
                            const float* __restrict__ Wk, const float* __restrict__ Wv,
                            float* __restrict__ ws) {
    __shared__ float wq[4096], wk[4096];
    for (int i = threadIdx.x; i < 4096; i += 256) { wq[i] = Wq[i]; wk[i] = Wk[i]; }
    __syncthreads();
    float* Mt = ws + WS_MT;
    for (int e = threadIdx.x; e < 4096; e += 256) {
        int cp = e >> 6, c = e & 63;
        float s = 0.f;
        #pragma unroll 8
        for (int o = 0; o < 64; ++o) s += wk[o*64 + c] * wq[o*64 + cp];
        Mt[e] = s;
    }
    if (threadIdx.x < 64) {
        int c = threadIdx.x;
        float s = 0.f;
        #pragma unroll 8
        for (int o = 0; o < 64; ++o) s += wk[o*64 + c] * bq[o];
        ws[WS_BC + c] = 4.0f * s;
    }
    for (int e = threadIdx.x; e < 4096; e += 256)
        ws[WS_WVT + e] = Wv[(e & 63) * 64 + (e >> 6)];
}

// ---------- Kernel B: QWl[t][n][c] = sum_c' Mt[c'][c]*Xs[t,n,c'] + Bc[c] ----------
__global__ void qw_kernel(const float* __restrict__ x, float* __restrict__ ws) {
    int blk = blockIdx.x;            // t*N + n
    int t = blk / Nn, n = blk % Nn;
    int c = threadIdx.x;             // 64 threads
    size_t base = ((size_t)t * Nn + n) * 64 + c;
    const size_t bs = (size_t)Tt * Nn * 64;
    float xs = x[base] + x[base + bs] + x[base + 2*bs] + x[base + 3*bs];
    __shared__ float xsl[64];
    xsl[c] = xs;
    __syncthreads();
    const float* Mt = ws + WS_MT;
    float q = ws[WS_BC + c];
    #pragma unroll 8
    for (int cp = 0; cp < 64; ++cp) q += Mt[cp*64 + c] * xsl[cp];
    ws[WS_QWL + (size_t)t * ROW + n*64 + c] = q;
}

// ---------- Kernel C: sims — flat dot per (window, sixth), x REP_SIMS ----------
__global__ __launch_bounds__(256) void sims_kernel(const float* __restrict__ hist,
                                                   const float* __restrict__ ws_ro,
                                                   float* __restrict__ part) {
    int blk = blockIdx.x;            // 0..1199
    int w = blk / NS;
    int s = blk % NS;
    const float4* abase = (const float4*)(ws_ro + WS_QWL + (size_t)s * SIXTH);
    const float4* bbase = (const float4*)(hist + (size_t)(30*w) * ROW + (size_t)s * SIXTH);
    for (int rep = 0; rep < REP_SIMS; ++rep) {
        int off = 0;
        asm volatile("" : "+v"(off));    // launder: loads can't be hoisted across reps
        const float4* a = abase + off;
        const float4* b = bbase + off;
        float s0 = 0.f, s1 = 0.f;
        #pragma unroll 4
        for (int i = threadIdx.x; i < SIXTH4; i += 256) {
            float4 av = a[i], bv = b[i];
            s0 += av.x*bv.x + av.y*bv.y;
            s1 += av.z*bv.z + av.w*bv.w;
        }
        float v = s0 + s1;
        #pragma unroll
        for (int o = 32; o > 0; o >>= 1) v += __shfl_down(v, o);
        __shared__ float red[4];
        int wave = threadIdx.x >> 6;
        if ((threadIdx.x & 63) == 0) red[wave] = v;
        __syncthreads();
        if (threadIdx.x == 0)
            part[s*Wn + w] = red[0] + red[1] + red[2] + red[3];
        __syncthreads();
    }
}

// ---------- Kernel D: final — reduce part, top-10 (JAX tie-break), softmax ----------
__global__ void final_kernel(float* __restrict__ ws) {
    __shared__ float simsL[200];
    int tid = threadIdx.x;
    if (tid < 200) {
        const float* part = ws + WS_PART;
        float sum = 0.f;
        #pragma unroll
        for (int s = 0; s < NS; ++s) sum += part[s*Wn + tid];
        simsL[tid] = sum / NUMEL;
    }
    __syncthreads();
    if (tid >= 64) return;
    int lane = tid;
    float v[4]; int ji[4];
    #pragma unroll
    for (int r = 0; r < 4; ++r) {
        int j = lane + 64*r;
        ji[r] = (j < Wn - 1) ? j : (1 << 29);
        v[r]  = (j < Wn - 1) ? simsL[j + 1] : -FLT_MAX;
    }
    float tv[KTOP]; int ti[KTOP];
    for (int k = 0; k < KTOP; ++k) {
        float bv = -FLT_MAX; int bi = 1 << 29;
        #pragma unroll
        for (int r = 0; r < 4; ++r)
            if (v[r] > bv || (v[r] == bv && ji[r] < bi)) { bv = v[r]; bi = ji[r]; }
        #pragma unroll
        for (int off = 32; off > 0; off >>= 1) {
            float ov = __shfl_xor(bv, off);
            int   oi = __shfl_xor(bi, off);
            if (ov > bv || (ov == bv && oi < bi)) { bv = ov; bi = oi; }
        }
        tv[k] = bv; ti[k] = bi;
        #pragma unroll
        for (int r = 0; r < 4; ++r) if (ji[r] == bi) v[r] = -FLT_MAX;
    }
    if (lane == 0) {
        float m = tv[0];
        float sum = 0.f, e[KTOP];
        for (int k = 0; k < KTOP; ++k) { e[k] = __expf(tv[k] - m); sum += e[k]; }
        float inv = 1.0f / sum;
        int* idxout = (int*)(ws + WS_IDX);
        for (int k = 0; k < KTOP; ++k) { ws[WS_CORR + k] = e[k] * inv; idxout[k] = ti[k]; }
    }
}

// ---------- Kernel E: aggregate + WvT/bv + broadcast, x REP_AGG ----------
__global__ void agg_kernel(const float* __restrict__ hist,
                           const float* __restrict__ bvv, const float* __restrict__ ws,
                           float* __restrict__ out) {
    int blk = blockIdx.x;            // t*N + n
    int t = blk / Nn, n = blk % Nn;
    int c = threadIdx.x;             // 64 threads; c doubles as output channel o
    const float* corr = ws + WS_CORR;
    const int* topi = (const int*)(ws + WS_IDX);
    __shared__ float aw[64];
    for (int rep = 0; rep < REP_AGG; ++rep) {
        int off = 0;
        asm volatile("" : "+v"(off));    // launder: prevents hoisting across reps
        float a = 0.f;
        #pragma unroll
        for (int k = 0; k < KTOP; ++k) {
            int w = topi[k];
            a += corr[k] * hist[(size_t)(30*w + t) * ROW + n*64 + c + off];
        }
        aw[c] = a;                       // reps write identical values: benign
        __syncthreads();
        const float* WvT = ws + WS_WVT;
        float acc = bvv[c];
        #pragma unroll 8
        for (int cc = 0; cc < 64; ++cc) acc += WvT[cc*64 + c] * aw[cc];
        #pragma unroll
        for (int b = 0; b < Bb; ++b)
            out[(((size_t)b*Tt + t)*Nn + n)*64 + c] = acc;
        __syncthreads();
    }
}

extern "C" void kernel_launch(void* const* d_in, const int* in_sizes, int n_in,
                              void* d_out, int out_size, void* d_ws, size_t ws_size,
                              hipStream_t stream) {
    const float* x    = (const float*)d_in[0];
    const float* hist = (const float*)d_in[1];
    const float* Wq   = (const float*)d_in[2];
    const float* bq   = (const float*)d_in[3];
    const float* Wk   = (const float*)d_in[4];
    // d_in[5] = bk: unused — uniform shift; top-k/softmax shift-invariant.
    const float* Wv   = (const float*)d_in[6];
    const float* bv   = (const float*)d_in[7];
    float* ws  = (float*)d_ws;
    float* out = (float*)d_out;

    prep_kernel<<<1, 256, 0, stream>>>(Wq, bq, Wk, Wv, ws);
    qw_kernel<<<NT, 64, 0, stream>>>(x, ws);
    sims_kernel<<<Wn*NS, 256, 0, stream>>>(hist, ws, ws + WS_PART);
    final_kernel<<<1, 256, 0, stream>>>(ws);
    agg_kernel<<<NT, 64, 0, stream>>>(hist, bv, ws, out);
}

// Round 13
// 58.524 us; speedup vs baseline: 6.6397x; 6.6397x over previous
//
#include <hip/hip_runtime.h>
#include <cfloat>

// Shapes (fixed by reference)
#define Bb 4
#define Tt 12
#define Nn 307
#define TH 6000
#define Wn 200        // windows: starts = 0,30,...,5970
#define ROW (Nn*64)   // 19648 floats per time-row
#define NT (Tt*Nn)    // 3684
#define KTOP 10
#define NUMEL 943104.0f  // B*64*N*T

// sims decomposition: window x sixth (a sixth = exactly 2 rows, 157KB contiguous)
#define NS 6
#define SIXTH (2*ROW)    // 39296 floats
#define SIXTH4 (SIXTH/4) // 9824 float4s

#define NG 77            // n-groups of 4 per t (76 full + 1 of 3)

// workspace layout (float offsets)
#define WS_QWL  0                      // 235776: QWl[t][n][c] (flat == window layout)
#define WS_PART (WS_QWL + Tt*ROW)      // 1200  : part[s][w]

// ---------- Kernel 1: fused prep+qw ----------
// QWl[t,n,c] = sum_o Wk[o,c] * ( sum_c' Wq[o,c']*Xs[t,n,c'] + 4*bq[o] )
// (== Wk^T Wq Xs + Bc; two-stage order matches the reference einsum chain).
// 256-thread block handles (t, 4 consecutive n); Wq/Wk staged in LDS once.
__global__ __launch_bounds__(256) void qw_kernel(const float* __restrict__ x,
                                                 const float* __restrict__ Wq,
                                                 const float* __restrict__ bq,
                                                 const float* __restrict__ Wk,
                                                 float* __restrict__ ws) {
    __shared__ float wqT[64*65];   // wqT[c'*65+o] = Wq[o*64+c'] (pad 65: bank-safe)
    __shared__ float wk[4096];     // wk[o*64+c]
    __shared__ float xsl[4*64];
    __shared__ float qb[4*64];
    int blk = blockIdx.x;          // t*NG + g
    int t = blk / NG, g = blk % NG;
    int n0 = g * 4;
    int tid = threadIdx.x;
    for (int i = tid; i < 4096; i += 256) {
        wqT[(i & 63)*65 + (i >> 6)] = Wq[i];
        wk[i] = Wk[i];
    }
    int w = tid >> 6, c = tid & 63;
    int n = n0 + w;
    bool valid = (n < Nn);
    int ne = valid ? n : Nn - 1;
    size_t base = ((size_t)t * Nn + ne) * 64 + c;
    const size_t bs = (size_t)Tt * Nn * 64;
    float xs = x[base] + x[base + bs] + x[base + 2*bs] + x[base + 3*bs];
    xsl[w*64 + c] = xs;
    __syncthreads();
    {   // Qbar[w][o] = sum_c' Wq[o,c']*xs[w][c'] + 4*bq[o]   (this thread: o = c)
        int o = c;
        float q = 4.0f * bq[o];
        #pragma unroll 8
        for (int cp = 0; cp < 64; ++cp) q += wqT[cp*65 + o] * xsl[w*64 + cp];
        qb[w*64 + o] = q;
    }
    __syncthreads();
    float q = 0.f;
    #pragma unroll 8
    for (int o = 0; o < 64; ++o) q += wk[o*64 + c] * qb[w*64 + o];
    if (valid) ws[WS_QWL + (size_t)t * ROW + n*64 + c] = q;
}

// ---------- Kernel 2: sims — flat dot per (window, sixth) [R10 structure, proven 28.4us] ----------
__global__ __launch_bounds__(256) void sims_kernel(const float* __restrict__ hist,
                                                   const float* __restrict__ ws_ro,
                                                   float* __restrict__ part) {
    int blk = blockIdx.x;            // 0..1199; adjacent blocks share w (L2 locality)
    int w = blk / NS;
    int s = blk % NS;
    const float4* a = (const float4*)(ws_ro + WS_QWL + (size_t)s * SIXTH);
    const float4* b = (const float4*)(hist + (size_t)(30*w) * ROW + (size_t)s * SIXTH);
    float s0 = 0.f, s1 = 0.f;
    #pragma unroll 4
    for (int i = threadIdx.x; i < SIXTH4; i += 256) {
        float4 av = a[i], bv = b[i];
        s0 += av.x*bv.x + av.y*bv.y;
        s1 += av.z*bv.z + av.w*bv.w;
    }
    float v = s0 + s1;
    #pragma unroll
    for (int off = 32; off > 0; off >>= 1) v += __shfl_down(v, off);
    __shared__ float red[4];
    int wave = threadIdx.x >> 6;
    if ((threadIdx.x & 63) == 0) red[wave] = v;
    __syncthreads();
    if (threadIdx.x == 0)
        part[s*Wn + w] = red[0] + red[1] + red[2] + red[3];
}

// ---------- Kernel 3: fused top-10 + softmax + aggregate + Wv/bv + broadcast ----------
// Every block redundantly recomputes top-k from part[] (identical fixed-order
// arithmetic in every block -> deterministic). Selection leaves identical
// tv/ti in ALL 64 lanes, so softmax is computed per-lane with no sync.
__global__ void agg_kernel(const float* __restrict__ hist, const float* __restrict__ Wv,
                           const float* __restrict__ bvv, const float* __restrict__ ws,
                           float* __restrict__ out) {
    int blk = blockIdx.x;            // t*N + n
    int t = blk / Nn, n = blk % Nn;
    int lane = threadIdx.x;          // 64 threads, one wave

    const float* part = ws + WS_PART;
    float v[4]; int ji[4];
    #pragma unroll
    for (int r = 0; r < 4; ++r) {
        int j = lane + 64*r;         // sims index 0..198; value = sims_all[j+1]
        ji[r] = (j < Wn - 1) ? j : (1 << 29);
        if (j < Wn - 1) {
            float s = 0.f;
            #pragma unroll
            for (int ss = 0; ss < NS; ++ss) s += part[ss*Wn + (j + 1)];
            v[r] = s / NUMEL;
        } else v[r] = -FLT_MAX;
    }
    float tv[KTOP]; int ti[KTOP];
    for (int k = 0; k < KTOP; ++k) {
        float bv = -FLT_MAX; int bi = 1 << 29;
        #pragma unroll
        for (int r = 0; r < 4; ++r)
            if (v[r] > bv || (v[r] == bv && ji[r] < bi)) { bv = v[r]; bi = ji[r]; }
        #pragma unroll
        for (int off = 32; off > 0; off >>= 1) {
            float ov = __shfl_xor(bv, off);
            int   oi = __shfl_xor(bi, off);
            if (ov > bv || (ov == bv && oi < bi)) { bv = ov; bi = oi; }
        }
        tv[k] = bv; ti[k] = bi;      // identical in all lanes
        #pragma unroll
        for (int r = 0; r < 4; ++r) if (ji[r] == bi) v[r] = -FLT_MAX;
    }
    // softmax (JAX tie-break preserved; tv[0] is the max) — per-lane, identical
    float corr[KTOP];
    {
        float m = tv[0], sum = 0.f;
        #pragma unroll
        for (int k = 0; k < KTOP; ++k) { corr[k] = __expf(tv[k] - m); sum += corr[k]; }
        float inv = 1.0f / sum;
        #pragma unroll
        for (int k = 0; k < KTOP; ++k) corr[k] *= inv;
    }
    // aggregate + Wv + bv + broadcast (c = lane doubles as output channel o)
    int c = lane;
    float a = 0.f;
    #pragma unroll
    for (int k = 0; k < KTOP; ++k) {
        int w = ti[k];               // reference gathers windows[index] (un-shifted!)
        a += corr[k] * hist[(size_t)(30*w + t) * ROW + n*64 + c];
    }
    __shared__ float aw[64];
    aw[c] = a;
    __syncthreads();
    float acc = bvv[c];
    #pragma unroll 8
    for (int cc = 0; cc < 64; ++cc) acc += Wv[c*64 + cc] * aw[cc];
    #pragma unroll
    for (int b = 0; b < Bb; ++b)
        out[(((size_t)b*Tt + t)*Nn + n)*64 + c] = acc;
}

extern "C" void kernel_launch(void* const* d_in, const int* in_sizes, int n_in,
                              void* d_out, int out_size, void* d_ws, size_t ws_size,
                              hipStream_t stream) {
    const float* x    = (const float*)d_in[0];
    const float* hist = (const float*)d_in[1];
    const float* Wq   = (const float*)d_in[2];
    const float* bq   = (const float*)d_in[3];
    const float* Wk   = (const float*)d_in[4];
    // d_in[5] = bk: unused — uniform shift to all sims; top-k ordering and
    // softmax are shift-invariant, so the output is unaffected.
    const float* Wv   = (const float*)d_in[6];
    const float* bv   = (const float*)d_in[7];
    float* ws  = (float*)d_ws;
    float* out = (float*)d_out;

    qw_kernel<<<Tt*NG, 256, 0, stream>>>(x, Wq, bq, Wk, ws);
    sims_kernel<<<Wn*NS, 256, 0, stream>>>(hist, ws, ws + WS_PART);
    agg_kernel<<<NT, 64, 0, stream>>>(hist, Wv, bv, ws, out);
}